// Round 2
// baseline (3872.342 us; speedup 1.0000x reference)
//
#include <hip/hip_runtime.h>

#define BB 8
#define CC 512
#define NN 2048
#define DD 64
#define KNN_K 16
#define PHID 64
#define AHID 256

// ---------------------------------------------------------------------------
// Generic f32 GEMM: out[b][m][n] = act( sum_k W[m][k] * X[b][k][n] + bias[m] )
// MODE: 0 = none, 1 = relu, 2 = add (out += add[b][m][n])
// STORE_T: store out[b][n][m] instead (for k/q/v transposed layouts)
// X is split: rows [0,K0) from X0, rows [K0,Ktot) from X1 (concat along K).
// ---------------------------------------------------------------------------
template<int MODE, bool STORE_T>
__global__ __launch_bounds__(256)
void gemm_f32(const float* __restrict__ W, const float* __restrict__ X0,
              const float* __restrict__ X1, int K0, int Ktot, int M, int Nn,
              const float* __restrict__ bias, const float* __restrict__ add,
              float* __restrict__ out)
{
    const int b  = blockIdx.z;
    const int n0 = blockIdx.x * 64;
    const int m0 = blockIdx.y * 64;
    const int tx = threadIdx.x, ty = threadIdx.y;
    const int tid = ty * 16 + tx;

    __shared__ float Ws[16][64];   // [k][m]
    __shared__ float Xs[16][64];   // [k][n]

    float acc[4][4] = {};

    const int wm = tid >> 2;          // 0..63 (m within tile)
    const int wkc = (tid & 3) * 4;    // 0,4,8,12 (k within tile)
    const int xc = tid >> 4;          // 0..15 (k within tile)
    const int xn = (tid & 15) * 4;    // n within tile

    for (int k0 = 0; k0 < Ktot; k0 += 16) {
        // W tile load (row-contig float4), store transposed [k][m]
        const float4 wv = *reinterpret_cast<const float4*>(
            &W[(size_t)(m0 + wm) * Ktot + k0 + wkc]);
        Ws[wkc + 0][wm] = wv.x;
        Ws[wkc + 1][wm] = wv.y;
        Ws[wkc + 2][wm] = wv.z;
        Ws[wkc + 3][wm] = wv.w;
        // X tile load (rows contiguous along n)
        const int kr = k0 + xc;
        const float* Xp = (kr < K0)
            ? (X0 + ((size_t)b * K0 + kr) * Nn)
            : (X1 + ((size_t)b * (Ktot - K0) + (kr - K0)) * Nn);
        *reinterpret_cast<float4*>(&Xs[xc][xn]) =
            *reinterpret_cast<const float4*>(&Xp[n0 + xn]);
        __syncthreads();

        #pragma unroll
        for (int kc = 0; kc < 16; ++kc) {
            const float4 a = *reinterpret_cast<const float4*>(&Ws[kc][ty * 4]);
            const float4 x = *reinterpret_cast<const float4*>(&Xs[kc][tx * 4]);
            acc[0][0] = fmaf(a.x, x.x, acc[0][0]);
            acc[0][1] = fmaf(a.x, x.y, acc[0][1]);
            acc[0][2] = fmaf(a.x, x.z, acc[0][2]);
            acc[0][3] = fmaf(a.x, x.w, acc[0][3]);
            acc[1][0] = fmaf(a.y, x.x, acc[1][0]);
            acc[1][1] = fmaf(a.y, x.y, acc[1][1]);
            acc[1][2] = fmaf(a.y, x.z, acc[1][2]);
            acc[1][3] = fmaf(a.y, x.w, acc[1][3]);
            acc[2][0] = fmaf(a.z, x.x, acc[2][0]);
            acc[2][1] = fmaf(a.z, x.y, acc[2][1]);
            acc[2][2] = fmaf(a.z, x.z, acc[2][2]);
            acc[2][3] = fmaf(a.z, x.w, acc[2][3]);
            acc[3][0] = fmaf(a.w, x.x, acc[3][0]);
            acc[3][1] = fmaf(a.w, x.y, acc[3][1]);
            acc[3][2] = fmaf(a.w, x.z, acc[3][2]);
            acc[3][3] = fmaf(a.w, x.w, acc[3][3]);
        }
        __syncthreads();
    }

    // Epilogue
    #pragma unroll
    for (int i = 0; i < 4; ++i) {
        const int m = m0 + ty * 4 + i;
        const float bsv = bias[m];
        float4 r = make_float4(acc[i][0] + bsv, acc[i][1] + bsv,
                               acc[i][2] + bsv, acc[i][3] + bsv);
        if (MODE == 1) {
            r.x = fmaxf(r.x, 0.f); r.y = fmaxf(r.y, 0.f);
            r.z = fmaxf(r.z, 0.f); r.w = fmaxf(r.w, 0.f);
        }
        const size_t nbase = (size_t)n0 + tx * 4;
        if (MODE == 2) {
            const float4 ad = *reinterpret_cast<const float4*>(
                &add[((size_t)b * M + m) * Nn + nbase]);
            r.x += ad.x; r.y += ad.y; r.z += ad.z; r.w += ad.w;
        }
        if (STORE_T) {
            out[((size_t)b * Nn + nbase + 0) * M + m] = r.x;
            out[((size_t)b * Nn + nbase + 1) * M + m] = r.y;
            out[((size_t)b * Nn + nbase + 2) * M + m] = r.z;
            out[((size_t)b * Nn + nbase + 3) * M + m] = r.w;
        } else {
            *reinterpret_cast<float4*>(&out[((size_t)b * M + m) * Nn + nbase]) = r;
        }
    }
}

// ---------------------------------------------------------------------------
// KNN: per (b,n) the 16 smallest squared distances (include self).
// All of batch b's positions staged in LDS; per-thread bubble-insert top-16
// with fully static register indexing (no scratch spill).
// ---------------------------------------------------------------------------
__global__ __launch_bounds__(256)
void knn_kernel(const float* __restrict__ pos, int* __restrict__ idx)
{
    const int b = blockIdx.y;
    const int tid = threadIdx.x;
    const int n = blockIdx.x * 256 + tid;

    __shared__ float px[NN], py[NN], pz[NN], sq[NN];
    for (int i = tid; i < NN; i += 256) {
        const float x = pos[((size_t)b * 3 + 0) * NN + i];
        const float y = pos[((size_t)b * 3 + 1) * NN + i];
        const float z = pos[((size_t)b * 3 + 2) * NN + i];
        px[i] = x; py[i] = y; pz[i] = z;
        sq[i] = x * x + y * y + z * z;
    }
    __syncthreads();

    const float cx = px[n], cy = py[n], cz = pz[n], cs = sq[n];
    float bd[KNN_K];
    int   bi[KNN_K];
    #pragma unroll
    for (int j = 0; j < KNN_K; ++j) { bd[j] = 3.4e38f; bi[j] = 0; }

    for (int m = 0; m < NN; ++m) {
        // d = |pn|^2 + |pm|^2 - 2 pn.pm
        float d = cs + sq[m];
        d = fmaf(-2.f * cx, px[m], d);
        d = fmaf(-2.f * cy, py[m], d);
        d = fmaf(-2.f * cz, pz[m], d);
        if (d < bd[KNN_K - 1]) {          // strict <: ties keep earlier index
            bd[KNN_K - 1] = d; bi[KNN_K - 1] = m;
            #pragma unroll
            for (int j = KNN_K - 1; j > 0; --j) {
                if (bd[j] < bd[j - 1]) {
                    const float td = bd[j]; bd[j] = bd[j - 1]; bd[j - 1] = td;
                    const int   ti = bi[j]; bi[j] = bi[j - 1]; bi[j - 1] = ti;
                }
            }
        }
    }
    #pragma unroll
    for (int j = 0; j < KNN_K; ++j)
        idx[((size_t)b * NN + n) * KNN_K + j] = bi[j];
}

// ---------------------------------------------------------------------------
// Fused per-point attention: one wave (64 threads, lane = d) per (b,n).
//   pe   = wp2 . relu(wp1 . pos_rel + bp1) + bp2          (per neighbor)
//   t    = (q - k_gathered) + pe
//   a1   = relu(wa1 . t + ba1)                            (256 hidden, 4 chunks)
//   attn = wa2 . a1 + ba2                                 (64 out)
//   softmax over the 16 neighbors (lane-local!), agg = sum attn*(v+pe)
// LDS ~12.5 KB -> ~12 blocks/CU.
// ---------------------------------------------------------------------------
__global__ __launch_bounds__(64)
void attn_kernel(const float* __restrict__ pos,
                 const float* __restrict__ kT, const float* __restrict__ qT,
                 const float* __restrict__ vT, const int* __restrict__ idxp,
                 const float* __restrict__ wp1, const float* __restrict__ bp1,
                 const float* __restrict__ wp2, const float* __restrict__ bp2,
                 const float* __restrict__ wa1, const float* __restrict__ ba1,
                 const float* __restrict__ wa2, const float* __restrict__ ba2,
                 float* __restrict__ agg)
{
    const int n = blockIdx.x, b = blockIdx.y, lane = threadIdx.x;

    __shared__ float t_s[KNN_K][DD];      // 4 KB
    __shared__ float pe_s[KNN_K][DD];     // 4 KB
    __shared__ float h_s[KNN_K][DD];      // 4 KB (pos-MLP hidden, then a1 chunk)
    __shared__ float rel_s[KNN_K][4];
    __shared__ int   idx_s[KNN_K];

    const float cx = pos[((size_t)b * 3 + 0) * NN + n];
    const float cy = pos[((size_t)b * 3 + 1) * NN + n];
    const float cz = pos[((size_t)b * 3 + 2) * NN + n];
    if (lane < KNN_K) {
        const int j = idxp[((size_t)b * NN + n) * KNN_K + lane];
        idx_s[lane] = j;
        rel_s[lane][0] = cx - pos[((size_t)b * 3 + 0) * NN + j];
        rel_s[lane][1] = cy - pos[((size_t)b * 3 + 1) * NN + j];
        rel_s[lane][2] = cz - pos[((size_t)b * 3 + 2) * NN + j];
    }
    __syncthreads();

    const float q_d = qT[((size_t)b * NN + n) * DD + lane];
    const float v_d = vT[((size_t)b * NN + n) * DD + lane];

    // ---- Phase 1a: pos-MLP hidden for ALL neighbors (lane = hidden unit) ---
    {
        const float w10 = wp1[lane * 3 + 0];
        const float w11 = wp1[lane * 3 + 1];
        const float w12 = wp1[lane * 3 + 2];
        const float b1l = bp1[lane];
        #pragma unroll
        for (int kk = 0; kk < KNN_K; ++kk) {
            const float hh = fmaf(w10, rel_s[kk][0],
                             fmaf(w11, rel_s[kk][1],
                             fmaf(w12, rel_s[kk][2], b1l)));
            h_s[kk][lane] = fmaxf(hh, 0.f);
        }
    }
    __syncthreads();

    // ---- Phase 1b: pe and t per neighbor (lane = output dim) --------------
    {
        const float b2l = bp2[lane];
        const float4* wp2row = reinterpret_cast<const float4*>(wp2 + lane * PHID);
        #pragma unroll
        for (int kk = 0; kk < KNN_K; ++kk) {
            float pe = b2l;
            #pragma unroll
            for (int i = 0; i < PHID / 4; ++i) {
                const float4 w = wp2row[i];
                const float4 hv = *reinterpret_cast<const float4*>(&h_s[kk][i * 4]);
                pe = fmaf(w.x, hv.x, fmaf(w.y, hv.y, fmaf(w.z, hv.z, fmaf(w.w, hv.w, pe))));
            }
            pe_s[kk][lane] = pe;
            const float kg = kT[((size_t)b * NN + idx_s[kk]) * DD + lane];
            t_s[kk][lane] = (q_d - kg) + pe;
        }
    }
    __syncthreads();

    // ---- Phase 2+3: attn = wa2 . relu(wa1 . t + ba1) + ba2, chunked by 64 --
    float at[KNN_K];
    {
        const float bb2 = ba2[lane];
        #pragma unroll
        for (int kk = 0; kk < KNN_K; ++kk) at[kk] = bb2;
    }
    for (int r = 0; r < AHID / DD; ++r) {
        const int hrow = r * 64 + lane;
        const float4* wrow = reinterpret_cast<const float4*>(wa1 + (size_t)hrow * DD);
        const float bb = ba1[hrow];
        float acc[KNN_K];
        #pragma unroll
        for (int kk = 0; kk < KNN_K; ++kk) acc[kk] = bb;
        #pragma unroll
        for (int dc = 0; dc < DD / 4; ++dc) {
            const float4 w = wrow[dc];
            #pragma unroll
            for (int kk = 0; kk < KNN_K; ++kk) {
                const float4 tv = *reinterpret_cast<const float4*>(&t_s[kk][dc * 4]);
                acc[kk] = fmaf(w.x, tv.x, fmaf(w.y, tv.y,
                          fmaf(w.z, tv.z, fmaf(w.w, tv.w, acc[kk]))));
            }
        }
        __syncthreads();   // h_s free (r=0: phase-1 consumers done; r>0: prev chunk consumed)
        #pragma unroll
        for (int kk = 0; kk < KNN_K; ++kk)
            h_s[kk][lane] = fmaxf(acc[kk], 0.f);     // a1 chunk [kk][h-within-chunk]
        __syncthreads();
        const float4* w2row = reinterpret_cast<const float4*>(wa2 + (size_t)lane * AHID + r * 64);
        #pragma unroll
        for (int hc = 0; hc < DD / 4; ++hc) {
            const float4 w = w2row[hc];
            #pragma unroll
            for (int kk = 0; kk < KNN_K; ++kk) {
                const float4 a = *reinterpret_cast<const float4*>(&h_s[kk][hc * 4]);
                at[kk] = fmaf(w.x, a.x, fmaf(w.y, a.y,
                         fmaf(w.z, a.z, fmaf(w.w, a.w, at[kk]))));
            }
        }
    }

    // ---- Phase 4: lane-local softmax over neighbors + aggregation ----------
    float mx = at[0];
    #pragma unroll
    for (int kk = 1; kk < KNN_K; ++kk) mx = fmaxf(mx, at[kk]);
    float s = 0.f;
    #pragma unroll
    for (int kk = 0; kk < KNN_K; ++kk) { at[kk] = expf(at[kk] - mx); s += at[kk]; }
    const float inv = 1.f / s;
    float accv = 0.f;
    #pragma unroll
    for (int kk = 0; kk < KNN_K; ++kk)
        accv = fmaf(at[kk], v_d + pe_s[kk][lane], accv);
    agg[((size_t)b * DD + lane) * NN + n] = accv * inv;
}

// ---------------------------------------------------------------------------
extern "C" void kernel_launch(void* const* d_in, const int* in_sizes, int n_in,
                              void* d_out, int out_size, void* d_ws, size_t ws_size,
                              hipStream_t stream)
{
    const float* pos   = (const float*)d_in[0];
    const float* key   = (const float*)d_in[1];
    const float* query = (const float*)d_in[2];
    const float* w1    = (const float*)d_in[3];
    const float* b1    = (const float*)d_in[4];
    const float* w2    = (const float*)d_in[5];
    const float* b2    = (const float*)d_in[6];
    const float* wsw   = (const float*)d_in[7];
    const float* bsb   = (const float*)d_in[8];
    const float* wk    = (const float*)d_in[9];
    const float* bk    = (const float*)d_in[10];
    const float* wq    = (const float*)d_in[11];
    const float* bq    = (const float*)d_in[12];
    const float* wv    = (const float*)d_in[13];
    const float* bv    = (const float*)d_in[14];
    const float* wp1   = (const float*)d_in[15];
    const float* bp1   = (const float*)d_in[16];
    const float* wp2   = (const float*)d_in[17];
    const float* bp2   = (const float*)d_in[18];
    const float* wa1   = (const float*)d_in[19];
    const float* ba1   = (const float*)d_in[20];
    const float* wa2   = (const float*)d_in[21];
    const float* ba2   = (const float*)d_in[22];
    const float* we    = (const float*)d_in[23];
    const float* be    = (const float*)d_in[24];

    float* ws = reinterpret_cast<float*>(d_ws);
    const size_t BCN = (size_t)BB * CC * NN;   // 8,388,608
    const size_t BND = (size_t)BB * NN * DD;   // 1,048,576
    float* value = ws;                 // (B,C,N)
    float* hbuf  = value + BCN;        // (B,C,N)
    float* kTbuf = hbuf + BCN;         // (B,N,D)
    float* qTbuf = kTbuf + BND;        // (B,N,D)
    float* vTbuf = qTbuf + BND;        // (B,N,D)
    float* aggb  = vTbuf + BND;        // (B,D,N)
    int*   idxb  = reinterpret_cast<int*>(aggb + BND);  // (B,N,16)

    const dim3 blk(16, 16);
    const dim3 gBig(NN / 64, CC / 64, BB);
    const dim3 gSmall(NN / 64, 1, BB);

    // value = W2.relu(W1.[key|query]+b1) + b2 + (Ws.[key|query]+bs)
    gemm_f32<1, false><<<gBig, blk, 0, stream>>>(w1,  key,  query, CC, 2 * CC, CC, NN, b1,  nullptr, hbuf);
    gemm_f32<0, false><<<gBig, blk, 0, stream>>>(wsw, key,  query, CC, 2 * CC, CC, NN, bsb, nullptr, value);
    gemm_f32<2, false><<<gBig, blk, 0, stream>>>(w2,  hbuf, nullptr, CC, CC, CC, NN, b2, value, value);

    // k/q/v projections, stored transposed (B,N,D)
    gemm_f32<0, true><<<gSmall, blk, 0, stream>>>(wk, key,   nullptr, CC, CC, DD, NN, bk, nullptr, kTbuf);
    gemm_f32<0, true><<<gSmall, blk, 0, stream>>>(wq, query, nullptr, CC, CC, DD, NN, bq, nullptr, qTbuf);
    gemm_f32<0, true><<<gSmall, blk, 0, stream>>>(wv, value, nullptr, CC, CC, DD, NN, bv, nullptr, vTbuf);

    // KNN top-16
    knn_kernel<<<dim3(NN / 256, BB), 256, 0, stream>>>(pos, idxb);

    // fused pos-MLP + attn-MLP + softmax + aggregation
    attn_kernel<<<dim3(NN, BB), 64, 0, stream>>>(pos, kTbuf, qTbuf, vTbuf, idxb,
                                                 wp1, bp1, wp2, bp2,
                                                 wa1, ba1, wa2, ba2, aggb);

    // out = we.agg + be + value
    gemm_f32<2, false><<<gBig, blk, 0, stream>>>(we, aggb, nullptr, DD, DD, CC, NN, be, value, (float*)d_out);
}

// Round 3
// 2044.288 us; speedup vs baseline: 1.8942x; 1.8942x over previous
//
#include <hip/hip_runtime.h>
#include <hip/hip_bf16.h>

#define BB 8
#define CC 512
#define NN 2048
#define DD 64
#define KNN_K 16
#define PHID 64
#define AHID 256

typedef __attribute__((ext_vector_type(4))) float f32x4;
typedef __attribute__((ext_vector_type(8))) short s16x8;

static __device__ __forceinline__ unsigned short f2bf(float x) {
    __hip_bfloat16 h = __float2bfloat16(x);
    return *reinterpret_cast<unsigned short*>(&h);
}
static __device__ __forceinline__ float bf2f(unsigned short u) {
    return __uint_as_float(((unsigned int)u) << 16);
}

// ---------------------------------------------------------------------------
// Generic f32 GEMM (unchanged from round 2)
// ---------------------------------------------------------------------------
template<int MODE, bool STORE_T>
__global__ __launch_bounds__(256)
void gemm_f32(const float* __restrict__ W, const float* __restrict__ X0,
              const float* __restrict__ X1, int K0, int Ktot, int M, int Nn,
              const float* __restrict__ bias, const float* __restrict__ add,
              float* __restrict__ out)
{
    const int b  = blockIdx.z;
    const int n0 = blockIdx.x * 64;
    const int m0 = blockIdx.y * 64;
    const int tx = threadIdx.x, ty = threadIdx.y;
    const int tid = ty * 16 + tx;

    __shared__ float Ws[16][64];
    __shared__ float Xs[16][64];

    float acc[4][4] = {};

    const int wm = tid >> 2;
    const int wkc = (tid & 3) * 4;
    const int xc = tid >> 4;
    const int xn = (tid & 15) * 4;

    for (int k0 = 0; k0 < Ktot; k0 += 16) {
        const float4 wv = *reinterpret_cast<const float4*>(
            &W[(size_t)(m0 + wm) * Ktot + k0 + wkc]);
        Ws[wkc + 0][wm] = wv.x;
        Ws[wkc + 1][wm] = wv.y;
        Ws[wkc + 2][wm] = wv.z;
        Ws[wkc + 3][wm] = wv.w;
        const int kr = k0 + xc;
        const float* Xp = (kr < K0)
            ? (X0 + ((size_t)b * K0 + kr) * Nn)
            : (X1 + ((size_t)b * (Ktot - K0) + (kr - K0)) * Nn);
        *reinterpret_cast<float4*>(&Xs[xc][xn]) =
            *reinterpret_cast<const float4*>(&Xp[n0 + xn]);
        __syncthreads();

        #pragma unroll
        for (int kc = 0; kc < 16; ++kc) {
            const float4 a = *reinterpret_cast<const float4*>(&Ws[kc][ty * 4]);
            const float4 x = *reinterpret_cast<const float4*>(&Xs[kc][tx * 4]);
            acc[0][0] = fmaf(a.x, x.x, acc[0][0]);
            acc[0][1] = fmaf(a.x, x.y, acc[0][1]);
            acc[0][2] = fmaf(a.x, x.z, acc[0][2]);
            acc[0][3] = fmaf(a.x, x.w, acc[0][3]);
            acc[1][0] = fmaf(a.y, x.x, acc[1][0]);
            acc[1][1] = fmaf(a.y, x.y, acc[1][1]);
            acc[1][2] = fmaf(a.y, x.z, acc[1][2]);
            acc[1][3] = fmaf(a.y, x.w, acc[1][3]);
            acc[2][0] = fmaf(a.z, x.x, acc[2][0]);
            acc[2][1] = fmaf(a.z, x.y, acc[2][1]);
            acc[2][2] = fmaf(a.z, x.z, acc[2][2]);
            acc[2][3] = fmaf(a.z, x.w, acc[2][3]);
            acc[3][0] = fmaf(a.w, x.x, acc[3][0]);
            acc[3][1] = fmaf(a.w, x.y, acc[3][1]);
            acc[3][2] = fmaf(a.w, x.z, acc[3][2]);
            acc[3][3] = fmaf(a.w, x.w, acc[3][3]);
        }
        __syncthreads();
    }

    #pragma unroll
    for (int i = 0; i < 4; ++i) {
        const int m = m0 + ty * 4 + i;
        const float bsv = bias[m];
        float4 r = make_float4(acc[i][0] + bsv, acc[i][1] + bsv,
                               acc[i][2] + bsv, acc[i][3] + bsv);
        if (MODE == 1) {
            r.x = fmaxf(r.x, 0.f); r.y = fmaxf(r.y, 0.f);
            r.z = fmaxf(r.z, 0.f); r.w = fmaxf(r.w, 0.f);
        }
        const size_t nbase = (size_t)n0 + tx * 4;
        if (MODE == 2) {
            const float4 ad = *reinterpret_cast<const float4*>(
                &add[((size_t)b * M + m) * Nn + nbase]);
            r.x += ad.x; r.y += ad.y; r.z += ad.z; r.w += ad.w;
        }
        if (STORE_T) {
            out[((size_t)b * Nn + nbase + 0) * M + m] = r.x;
            out[((size_t)b * Nn + nbase + 1) * M + m] = r.y;
            out[((size_t)b * Nn + nbase + 2) * M + m] = r.z;
            out[((size_t)b * Nn + nbase + 3) * M + m] = r.w;
        } else {
            *reinterpret_cast<float4*>(&out[((size_t)b * M + m) * Nn + nbase]) = r;
        }
    }
}

// ---------------------------------------------------------------------------
// KNN (unchanged)
// ---------------------------------------------------------------------------
__global__ __launch_bounds__(256)
void knn_kernel(const float* __restrict__ pos, int* __restrict__ idx)
{
    const int b = blockIdx.y;
    const int tid = threadIdx.x;
    const int n = blockIdx.x * 256 + tid;

    __shared__ float px[NN], py[NN], pz[NN], sq[NN];
    for (int i = tid; i < NN; i += 256) {
        const float x = pos[((size_t)b * 3 + 0) * NN + i];
        const float y = pos[((size_t)b * 3 + 1) * NN + i];
        const float z = pos[((size_t)b * 3 + 2) * NN + i];
        px[i] = x; py[i] = y; pz[i] = z;
        sq[i] = x * x + y * y + z * z;
    }
    __syncthreads();

    const float cx = px[n], cy = py[n], cz = pz[n], cs = sq[n];
    float bd[KNN_K];
    int   bi[KNN_K];
    #pragma unroll
    for (int j = 0; j < KNN_K; ++j) { bd[j] = 3.4e38f; bi[j] = 0; }

    for (int m = 0; m < NN; ++m) {
        float d = cs + sq[m];
        d = fmaf(-2.f * cx, px[m], d);
        d = fmaf(-2.f * cy, py[m], d);
        d = fmaf(-2.f * cz, pz[m], d);
        if (d < bd[KNN_K - 1]) {
            bd[KNN_K - 1] = d; bi[KNN_K - 1] = m;
            #pragma unroll
            for (int j = KNN_K - 1; j > 0; --j) {
                if (bd[j] < bd[j - 1]) {
                    const float td = bd[j]; bd[j] = bd[j - 1]; bd[j - 1] = td;
                    const int   ti = bi[j]; bi[j] = bi[j - 1]; bi[j - 1] = ti;
                }
            }
        }
    }
    #pragma unroll
    for (int j = 0; j < KNN_K; ++j)
        idx[((size_t)b * NN + n) * KNN_K + j] = bi[j];
}

// ---------------------------------------------------------------------------
// prep_weights: f32 wa1 (256x64), wa2 (64x256) -> bf16, pre-arranged in MFMA
// A-fragment order (lane-consecutive 16B chunks per (chunk,kstep,mtile)).
// ---------------------------------------------------------------------------
__global__ __launch_bounds__(256)
void prep_weights(const float* __restrict__ wa1, const float* __restrict__ wa2,
                  short* __restrict__ wa1arr, short* __restrict__ wa2arr)
{
    const int t = blockIdx.x * 256 + threadIdx.x;   // 0..32767
    if (t < 16384) {
        const int h = t >> 6, kd = t & 63;           // wa1[h][kd]
        const int hc = h >> 6, mt = (h >> 4) & 3, rl = h & 15;
        const int ks = kd >> 5, g = (kd >> 3) & 3, j = kd & 7;
        const int p = (((hc * 4 + mt) * 2 + ks) * 64 + g * 16 + rl) * 8 + j;
        wa1arr[p] = f2bf(wa1[t]);
    } else {
        const int t2 = t - 16384;
        const int r = t2 >> 8, kh = t2 & 255;        // wa2[r][kh]
        const int mt2 = r >> 4, rl = r & 15;
        const int hc = kh >> 6, ks2 = (kh >> 5) & 1, g = (kh >> 3) & 3, j = kh & 7;
        const int p = (((hc * 2 + ks2) * 4 + mt2) * 64 + g * 16 + rl) * 8 + j;
        wa2arr[p] = f2bf(wa2[t2]);
    }
}

// ---------------------------------------------------------------------------
// prep_cols: per column (b,n,kk): pos-MLP pe, t = q - k_g + pe (bf16, written
// pre-arranged as MFMA B-fragments), vpe = v + pe (bf16, row layout [col][d]).
// 4 waves/block, each wave 2 columns, lane = d.
// ---------------------------------------------------------------------------
__global__ __launch_bounds__(256)
void prep_cols(const float* __restrict__ pos,
               const float* __restrict__ kT, const float* __restrict__ qT,
               const float* __restrict__ vT, const int* __restrict__ idxp,
               const float* __restrict__ wp1, const float* __restrict__ bp1,
               const float* __restrict__ wp2, const float* __restrict__ bp2,
               short* __restrict__ tarr, short* __restrict__ vpe)
{
    const int lane = threadIdx.x & 63;      // = d
    const int w = threadIdx.x >> 6;
    __shared__ float hsh[4][2][64];

    const int cbase = (blockIdx.x * 4 + w) * 2;

    const float w0 = wp1[lane * 3 + 0];
    const float w1 = wp1[lane * 3 + 1];
    const float w2 = wp1[lane * 3 + 2];
    const float b1 = bp1[lane], b2 = bp2[lane];

    int bn[2], jj[2];
    #pragma unroll
    for (int u = 0; u < 2; ++u) {
        const int col = cbase + u;
        bn[u] = col >> 4;
        const int b = bn[u] >> 11, n = bn[u] & 2047;
        const int j = idxp[col];
        jj[u] = j;
        const float rx = pos[((size_t)b * 3 + 0) * NN + n] - pos[((size_t)b * 3 + 0) * NN + j];
        const float ry = pos[((size_t)b * 3 + 1) * NN + n] - pos[((size_t)b * 3 + 1) * NN + j];
        const float rz = pos[((size_t)b * 3 + 2) * NN + n] - pos[((size_t)b * 3 + 2) * NN + j];
        const float hh = fmaf(w0, rx, fmaf(w1, ry, fmaf(w2, rz, b1)));
        hsh[w][u][lane] = fmaxf(hh, 0.f);
    }
    __syncthreads();

    float pe[2] = {b2, b2};
    const float4* wrow = reinterpret_cast<const float4*>(wp2 + (size_t)lane * PHID);
    #pragma unroll
    for (int i = 0; i < 16; ++i) {
        const float4 ww = wrow[i];
        #pragma unroll
        for (int u = 0; u < 2; ++u) {
            const float4 hv = *reinterpret_cast<const float4*>(&hsh[w][u][i * 4]);
            pe[u] = fmaf(ww.x, hv.x, fmaf(ww.y, hv.y,
                    fmaf(ww.z, hv.z, fmaf(ww.w, hv.w, pe[u]))));
        }
    }

    const int ks = lane >> 5, g = (lane >> 3) & 3, je = lane & 7;
    #pragma unroll
    for (int u = 0; u < 2; ++u) {
        const int col = cbase + u;
        const int b = bn[u] >> 11;
        const float qd = qT[(size_t)bn[u] * DD + lane];
        const float kd = kT[((size_t)(b << 11) + jj[u]) * DD + lane];
        const float vd = vT[(size_t)bn[u] * DD + lane];
        const float tval = (qd - kd) + pe[u];
        const int ct = col >> 4, cl = col & 15;
        tarr[(size_t)ct * 1024 + ks * 512 + (g * 16 + cl) * 8 + je] = f2bf(tval);
        vpe[(size_t)col * DD + lane] = f2bf(vd + pe[u]);
    }
}

// ---------------------------------------------------------------------------
// attn_mfma: attn = wa2 . relu(wa1 . t + ba1) + ba2  (MFMA, bf16), then
// softmax over the 16 kk (= 16 cols of one fragment -> shfl_xor groups),
// agg = sum attn * vpe. Block = 4 waves x 32 cols (2 coltiles) each.
// Inputs t/weights come straight from global as pre-arranged fragments;
// only the a1 D->B handoff uses (wave-private, XOR-swizzled) LDS.
// ---------------------------------------------------------------------------
__global__ __launch_bounds__(256)
void attn_mfma(const short* __restrict__ tarr, const short* __restrict__ vpe,
               const short* __restrict__ wa1arr, const short* __restrict__ wa2arr,
               const float* __restrict__ ba1, const float* __restrict__ ba2,
               float* __restrict__ aggb)
{
    __shared__ __align__(16) char a1lds[16384];
    const int lane = threadIdx.x & 63;
    const int w = threadIdx.x >> 6;
    const int cl = lane & 15, gq = lane >> 4;
    char* wbase = a1lds + w * 4096;
    const int ntb = blockIdx.x * 8 + w * 2;

    // t fragments for this wave's 32 columns (held for all 4 hidden chunks)
    s16x8 tf[2][2];
    #pragma unroll
    for (int nt2 = 0; nt2 < 2; ++nt2)
        #pragma unroll
        for (int ks = 0; ks < 2; ++ks)
            tf[nt2][ks] = *reinterpret_cast<const s16x8*>(
                tarr + (size_t)(ntb + nt2) * 1024 + ks * 512 + lane * 8);

    f32x4 acc2[4][2];
    #pragma unroll
    for (int m = 0; m < 4; ++m)
        #pragma unroll
        for (int n = 0; n < 2; ++n)
            acc2[m][n] = (f32x4){0.f, 0.f, 0.f, 0.f};

    for (int hc = 0; hc < 4; ++hc) {
        // ---- a1 chunk = relu(wa1_chunk . t + ba1) -------------------------
        f32x4 a1acc[4][2];
        #pragma unroll
        for (int mt = 0; mt < 4; ++mt) {
            const float4 bi = *reinterpret_cast<const float4*>(
                ba1 + hc * 64 + mt * 16 + gq * 4);
            const f32x4 b4 = {bi.x, bi.y, bi.z, bi.w};
            a1acc[mt][0] = b4;
            a1acc[mt][1] = b4;
        }
        #pragma unroll
        for (int ks = 0; ks < 2; ++ks) {
            #pragma unroll
            for (int mt = 0; mt < 4; ++mt) {
                const s16x8 wf = *reinterpret_cast<const s16x8*>(
                    wa1arr + (size_t)(((hc * 4 + mt) * 2 + ks) * 64 + lane) * 8);
                #pragma unroll
                for (int nt2 = 0; nt2 < 2; ++nt2)
                    a1acc[mt][nt2] = __builtin_amdgcn_mfma_f32_16x16x32_bf16(
                        wf, tf[nt2][ks], a1acc[mt][nt2], 0, 0, 0);
            }
        }
        __syncthreads();   // previous chunk's LDS reads done everywhere
        // relu + cvt + store D-frags to wave-private swizzled LDS [col][h]
        #pragma unroll
        for (int mt = 0; mt < 4; ++mt) {
            #pragma unroll
            for (int nt2 = 0; nt2 < 2; ++nt2) {
                const int c = nt2 * 16 + cl;
                const int r0 = mt * 16 + gq * 4;
                const f32x4 v = a1acc[mt][nt2];
                const unsigned int p01 =
                    (unsigned int)f2bf(fmaxf(v[0], 0.f)) |
                    ((unsigned int)f2bf(fmaxf(v[1], 0.f)) << 16);
                const unsigned int p23 =
                    (unsigned int)f2bf(fmaxf(v[2], 0.f)) |
                    ((unsigned int)f2bf(fmaxf(v[3], 0.f)) << 16);
                const int byte = (c * 128 + r0 * 2) ^ ((c & 7) << 4);
                *reinterpret_cast<uint2*>(wbase + byte) = make_uint2(p01, p23);
            }
        }
        __syncthreads();
        // ---- attn += wa2_chunk . a1_chunk ---------------------------------
        #pragma unroll
        for (int ks2 = 0; ks2 < 2; ++ks2) {
            s16x8 bfr[2];
            #pragma unroll
            for (int nt2 = 0; nt2 < 2; ++nt2) {
                const int c = nt2 * 16 + cl;
                const int byte = (c * 128 + ks2 * 64 + gq * 16) ^ ((c & 7) << 4);
                bfr[nt2] = *reinterpret_cast<const s16x8*>(wbase + byte);
            }
            #pragma unroll
            for (int mt2 = 0; mt2 < 4; ++mt2) {
                const s16x8 wf2 = *reinterpret_cast<const s16x8*>(
                    wa2arr + (size_t)(((hc * 2 + ks2) * 4 + mt2) * 64 + lane) * 8);
                #pragma unroll
                for (int nt2 = 0; nt2 < 2; ++nt2)
                    acc2[mt2][nt2] = __builtin_amdgcn_mfma_f32_16x16x32_bf16(
                        wf2, bfr[nt2], acc2[mt2][nt2], 0, 0, 0);
            }
        }
    }

    // ---- epilogue: +ba2, softmax over kk (16 lanes of group), agg ----------
    #pragma unroll
    for (int nt2 = 0; nt2 < 2; ++nt2) {
        const int nt = ntb + nt2;           // = global (b,n) group
        const int b = nt >> 11, n = nt & 2047;
        const int col = nt * 16 + cl;       // kk = cl
        #pragma unroll
        for (int mt2 = 0; mt2 < 4; ++mt2) {
            const int r0 = mt2 * 16 + gq * 4;
            const float4 bb = *reinterpret_cast<const float4*>(ba2 + r0);
            const uint2 pv = *reinterpret_cast<const uint2*>(
                vpe + (size_t)col * DD + r0);
            const float vp[4] = {
                bf2f((unsigned short)(pv.x & 0xffff)),
                bf2f((unsigned short)(pv.x >> 16)),
                bf2f((unsigned short)(pv.y & 0xffff)),
                bf2f((unsigned short)(pv.y >> 16))};
            const float bbv[4] = {bb.x, bb.y, bb.z, bb.w};
            #pragma unroll
            for (int reg = 0; reg < 4; ++reg) {
                const float logit = acc2[mt2][nt2][reg] + bbv[reg];
                float mx = logit;
                mx = fmaxf(mx, __shfl_xor(mx, 1));
                mx = fmaxf(mx, __shfl_xor(mx, 2));
                mx = fmaxf(mx, __shfl_xor(mx, 4));
                mx = fmaxf(mx, __shfl_xor(mx, 8));
                const float e = expf(logit - mx);
                float num = e * vp[reg];
                float den = e;
                num += __shfl_xor(num, 1); den += __shfl_xor(den, 1);
                num += __shfl_xor(num, 2); den += __shfl_xor(den, 2);
                num += __shfl_xor(num, 4); den += __shfl_xor(den, 4);
                num += __shfl_xor(num, 8); den += __shfl_xor(den, 8);
                if (cl == 0)
                    aggb[((size_t)b * DD + r0 + reg) * NN + n] = num / den;
            }
        }
    }
}

// ---------------------------------------------------------------------------
extern "C" void kernel_launch(void* const* d_in, const int* in_sizes, int n_in,
                              void* d_out, int out_size, void* d_ws, size_t ws_size,
                              hipStream_t stream)
{
    const float* pos   = (const float*)d_in[0];
    const float* key   = (const float*)d_in[1];
    const float* query = (const float*)d_in[2];
    const float* w1    = (const float*)d_in[3];
    const float* b1    = (const float*)d_in[4];
    const float* w2    = (const float*)d_in[5];
    const float* b2    = (const float*)d_in[6];
    const float* wsw   = (const float*)d_in[7];
    const float* bsb   = (const float*)d_in[8];
    const float* wk    = (const float*)d_in[9];
    const float* bk    = (const float*)d_in[10];
    const float* wq    = (const float*)d_in[11];
    const float* bq    = (const float*)d_in[12];
    const float* wv    = (const float*)d_in[13];
    const float* bv    = (const float*)d_in[14];
    const float* wp1   = (const float*)d_in[15];
    const float* bp1   = (const float*)d_in[16];
    const float* wp2   = (const float*)d_in[17];
    const float* bp2   = (const float*)d_in[18];
    const float* wa1   = (const float*)d_in[19];
    const float* ba1   = (const float*)d_in[20];
    const float* wa2   = (const float*)d_in[21];
    const float* ba2   = (const float*)d_in[22];
    const float* we    = (const float*)d_in[23];
    const float* be    = (const float*)d_in[24];

    float* ws = reinterpret_cast<float*>(d_ws);
    const size_t BCN = (size_t)BB * CC * NN;       // 8,388,608
    const size_t BND = (size_t)BB * NN * DD;       // 1,048,576
    const size_t NCOLS = (size_t)BB * NN * KNN_K;  // 262,144
    float* value = ws;                   // (B,C,N) f32
    float* hbuf  = value + BCN;          // (B,C,N) f32 -> reused as tarr
    float* kTbuf = hbuf + BCN;           // (B,N,D) f32
    float* qTbuf = kTbuf + BND;
    float* vTbuf = qTbuf + BND;
    float* aggb  = vTbuf + BND;          // (B,D,N) f32
    int*   idxb  = reinterpret_cast<int*>(aggb + BND);      // (B,N,16)
    short* vpe    = reinterpret_cast<short*>(idxb + NCOLS); // (cols, 64) bf16
    short* wa1arr = vpe + NCOLS * DD;                       // 16384 bf16
    short* wa2arr = wa1arr + 16384;                         // 16384 bf16
    short* tarr   = reinterpret_cast<short*>(hbuf);         // frag-arranged bf16

    const dim3 blk(16, 16);
    const dim3 gBig(NN / 64, CC / 64, BB);
    const dim3 gSmall(NN / 64, 1, BB);

    prep_weights<<<128, 256, 0, stream>>>(wa1, wa2, wa1arr, wa2arr);

    // value = W2.relu(W1.[key|query]+b1) + b2 + (Ws.[key|query]+bs)
    gemm_f32<1, false><<<gBig, blk, 0, stream>>>(w1,  key,  query, CC, 2 * CC, CC, NN, b1,  nullptr, hbuf);
    gemm_f32<0, false><<<gBig, blk, 0, stream>>>(wsw, key,  query, CC, 2 * CC, CC, NN, bsb, nullptr, value);
    gemm_f32<2, false><<<gBig, blk, 0, stream>>>(w2,  hbuf, nullptr, CC, CC, CC, NN, b2, value, value);

    // k/q/v projections, stored transposed (B,N,D)
    gemm_f32<0, true><<<gSmall, blk, 0, stream>>>(wk, key,   nullptr, CC, CC, DD, NN, bk, nullptr, kTbuf);
    gemm_f32<0, true><<<gSmall, blk, 0, stream>>>(wq, query, nullptr, CC, CC, DD, NN, bq, nullptr, qTbuf);
    gemm_f32<0, true><<<gSmall, blk, 0, stream>>>(wv, value, nullptr, CC, CC, DD, NN, bv, nullptr, vTbuf);

    // KNN top-16
    knn_kernel<<<dim3(NN / 256, BB), 256, 0, stream>>>(pos, idxb);

    // per-column pos-MLP + t/vpe prep (overwrites hbuf with tarr — hbuf dead)
    prep_cols<<<dim3(NCOLS / 8), 256, 0, stream>>>(pos, kTbuf, qTbuf, vTbuf, idxb,
                                                   wp1, bp1, wp2, bp2, tarr, vpe);

    // fused MFMA attn-MLP + softmax + aggregation
    attn_mfma<<<dim3(NCOLS / 128), 256, 0, stream>>>(tarr, vpe, wa1arr, wa2arr,
                                                     ba1, ba2, aggb);

    // out = we.agg + be + value
    gemm_f32<2, false><<<gBig, blk, 0, stream>>>(we, aggb, nullptr, DD, DD, CC, NN, be, value, (float*)d_out);
}